// Round 6
// baseline (721.294 us; speedup 1.0000x reference)
//
#include <hip/hip_runtime.h>
#include <hip/hip_bf16.h>
#include <cstdint>

typedef unsigned short u16;
typedef __attribute__((ext_vector_type(8))) _Float16 f16x8;
typedef __attribute__((ext_vector_type(4))) float f32x4;
typedef __attribute__((ext_vector_type(8))) unsigned short u16x8;

typedef const __attribute__((address_space(1))) void* gas1p;
typedef __attribute__((address_space(3))) void* las3p;

__device__ __forceinline__ void gld_lds16(const void* g, void* l) {
    __builtin_amdgcn_global_load_lds((gas1p)g, (las3p)l, 16, 0, 0);
}

__device__ __forceinline__ u16 f2h(float f) {
    _Float16 h = (_Float16)f;
    return __builtin_bit_cast(u16, h);
}

// ---------------- prep: x fp32 -> fp16 ----------------
__global__ void cvt_x_kernel(const float4* __restrict__ x, u16* __restrict__ xb) {
    size_t i = (size_t)blockIdx.x * blockDim.x + threadIdx.x;
    float4 a = x[2 * i];
    float4 b = x[2 * i + 1];
    u16x8 o;
    o[0] = f2h(a.x); o[1] = f2h(a.y); o[2] = f2h(a.z); o[3] = f2h(a.w);
    o[4] = f2h(b.x); o[5] = f2h(b.y); o[6] = f2h(b.z); o[7] = f2h(b.w);
    *(u16x8*)&xb[i * 8] = o;
}

// ---------------- prep: weight norm, all 5 layers in 2 launches ----------------
struct WnDesc {
    const float* v; const float* g; u16* wT; float* partial;
    int K; int N; int blk0;
};
struct WnPack { WnDesc d[5]; int nlayer; };

__global__ void wn_partial_all(WnPack p) {
    int b = blockIdx.x;
    int l = 0;
    while (l + 1 < p.nlayer && b >= p.d[l + 1].blk0) l++;
    const WnDesc& d = p.d[l];
    int lb = b - d.blk0;
    int nbx = d.N >> 6;
    int bx = lb % nbx, seg = lb / nbx;

    int lane = threadIdx.x & 63;
    int tr = threadIdx.x >> 6;
    int n = bx * 64 + lane;
    int kseg = d.K >> 3;
    int kbeg = seg * kseg;
    float s = 0.f;
    for (int k = kbeg + tr; k < kbeg + kseg; k += 4) {
        float x = d.v[(size_t)k * d.N + n];
        s += x * x;
    }
    __shared__ float red[4][64];
    red[tr][lane] = s;
    __syncthreads();
    if (tr == 0)
        d.partial[seg * d.N + n] = red[0][lane] + red[1][lane] + red[2][lane] + red[3][lane];
}

__global__ void wn_write_all(WnPack p) {
    int b = blockIdx.x;
    int l = 0;
    while (l + 1 < p.nlayer && b >= p.d[l + 1].blk0) l++;
    const WnDesc& d = p.d[l];
    int lb = b - d.blk0;
    int nbx = d.N >> 6;
    int bx = lb % nbx, seg = lb / nbx;

    int lane = threadIdx.x & 63;
    int tr = threadIdx.x >> 6;
    int n = bx * 64 + lane;
    float s = 0.f;
#pragma unroll
    for (int i = 0; i < 8; i++) s += d.partial[i * d.N + n];
    float sc = d.g[n] / sqrtf(s);

    int kseg = d.K >> 3;
    int kbeg = seg * kseg;
    for (int k = kbeg + tr; k < kbeg + kseg; k += 4)
        d.wT[(size_t)n * d.K + k] = f2h(d.v[(size_t)k * d.N + n] * sc);
}

// ---------------- main GEMM: 256x256, BK=64, 8 waves, m201-conformant 8-phase --
// Phase = { ds_reads ; stage(2 gld_lds) ; [lgkm throttle] ; [vmcnt drain] ;
//           BAR ; 16 MFMA (setprio) ; BAR }.
// Stage ring (this-iter actions), depth-6 counted drains at P4/P8:
//   P1:A1(tb)  P2:A0(ta+2)  P3:B0(ta+2)  P4:B1(ta+2)+vmcnt(6)
//   P5:A1(ta+2) P6:A0(tb+2) P7:B0(tb+2)  P8:B1(tb+2)+vmcnt(6)
// RAW: P4 drain forces prev{A0b,B0b,B1b}+this{A1b} (read P5-P7);
//      P8 drain forces this{A0a',B0a',B1a',A1a'} (read next P1-P3).
// WAR: every stage's target region last-read one full (double-barriered)
//      phase earlier -> all readers' lgkm(0) completed before stage issue.
template<int N, int K, bool ACT, bool OUTF32>
__global__ __launch_bounds__(512, 2) void gemm_mlp(
    const u16* __restrict__ A, const u16* __restrict__ Bt,
    u16* __restrict__ Ch, float* __restrict__ Cf)
{
    constexpr int M = 65536;
    constexpr int NT = K / 64;      // K-tiles (even, >=4)
    constexpr int J = NT / 2;       // iterations
    constexpr int NTN = N / 256;
    constexpr int NWG = (M / 256) * NTN;

    __shared__ u16 sA[2][256 * 64];
    __shared__ u16 sB[2][2 * 128 * 64];

    const int bid = blockIdx.x;
    const int wk = (bid & 7) * (NWG >> 3) + (bid >> 3);   // bijective: NWG%8==0
    const int tm = wk / NTN, tn = wk % NTN;
    const long m0 = (long)tm * 256;
    const int n0 = tn * 256;

    const int tid = threadIdx.x;
    const int lane = tid & 63;
    const int wid = tid >> 6;
    const int wm = (wid >> 2) * 128;
    const int wn = (wid & 3) * 64;

    const int r8 = tid >> 3;
    const int gcol = ((tid & 7) ^ (r8 & 7)) * 8;
    const u16* Abase = A + (m0 + r8) * (size_t)K + gcol;
    const u16* Bbase = Bt + (size_t)(n0 + ((r8 >> 5) * 64 + (r8 & 31))) * K + gcol;
    const int dst8 = tid * 8;

    const u16* Aq0 = Abase;
    const u16* Aq1 = Abase + (size_t)64 * K;
    const u16* Aq2 = Abase + (size_t)128 * K;
    const u16* Aq3 = Abase + (size_t)192 * K;
    const u16* B00 = Bbase;
    const u16* B01 = Bbase + (size_t)128 * K;
    const u16* B10 = Bbase + (size_t)32 * K;
    const u16* B11 = Bbase + (size_t)160 * K;

    auto stA = [&](int buf, const u16* base, int t, int q) {
        gld_lds16(base + (size_t)t * 64, &sA[buf][q * 4096 + dst8]);
    };
    auto stB = [&](int buf, const u16* base, int t, int s, int c) {
        gld_lds16(base + (size_t)t * 64, &sB[buf][s * 8192 + c * 4096 + dst8]);
    };
    // half-tile stagers (2 gld_lds each)
    auto stA0 = [&](int buf, int t) { stA(buf, Aq0, t, 0); stA(buf, Aq2, t, 2); };
    auto stA1 = [&](int buf, int t) { stA(buf, Aq1, t, 1); stA(buf, Aq3, t, 3); };
    auto stB0 = [&](int buf, int t) { stB(buf, B00, t, 0, 0); stB(buf, B01, t, 0, 1); };
    auto stB1 = [&](int buf, int t) { stB(buf, B10, t, 1, 0); stB(buf, B11, t, 1, 1); };

    const int rbase = lane & 15;
    const int co0 = ((lane >> 4) ^ (lane & 7)) * 8;
    const int arow0 = (wm + rbase) * 64 + co0;
    const int brow0 = ((wn >> 6) * 32 + rbase) * 64 + co0;

    f32x4 acc[8][4] = {};
    f16x8 a[4][2], bq[2][2][2];

    auto ldA = [&](int buf, int qm) {
#pragma unroll
        for (int i = 0; i < 4; i++) {
            int base = arow0 + (qm * 64 + i * 16) * 64;
            a[i][0] = *(const f16x8*)&sA[buf][base];
            a[i][1] = *(const f16x8*)&sA[buf][base ^ 32];
        }
    };
    auto ldB = [&](int buf, int qn) {
#pragma unroll
        for (int j2 = 0; j2 < 2; j2++) {
            int base = brow0 + qn * 8192 + j2 * 1024;
            bq[qn][j2][0] = *(const f16x8*)&sB[buf][base];
            bq[qn][j2][1] = *(const f16x8*)&sB[buf][base ^ 32];
        }
    };
    auto mmaq = [&](int qm, int qn) {
        __builtin_amdgcn_s_setprio(1);
#pragma unroll
        for (int kk = 0; kk < 2; kk++)
#pragma unroll
            for (int i = 0; i < 4; i++)
#pragma unroll
                for (int j2 = 0; j2 < 2; j2++)
                    acc[qm * 4 + i][qn * 2 + j2] = __builtin_amdgcn_mfma_f32_16x16x32_f16(
                        a[i][kk], bq[qn][j2][kk], acc[qm * 4 + i][qn * 2 + j2], 0, 0, 0);
        __builtin_amdgcn_s_setprio(0);
    };
    auto bar = [&]() {
        asm volatile("" ::: "memory");
        __builtin_amdgcn_s_barrier();
        asm volatile("" ::: "memory");
    };

    // ---- prologue: 7 half-tile stages; drain forces tile0's 4 halves ----
    stA0(0, 0); stB0(0, 0); stB1(0, 0); stA1(0, 0);
    stA0(1, 1); stB0(1, 1); stB1(1, 1);
    asm volatile("s_waitcnt vmcnt(6)" ::: "memory");
    bar();

    // ---- main loop (uniform for j in [0, J-1)) ----
    for (int j = 0; j < J - 1; j++) {
        const int ta = 2 * j, tb = ta + 1;
        // P1: reads A0a,B0a (12) | stage A1(tb)
        ldA(0, 0); ldB(0, 0);
        stA1(1, tb);
        asm volatile("s_waitcnt lgkmcnt(8)" ::: "memory");
        bar();
        mmaq(0, 0);
        bar();
        // P2: reads B1a (4) | stage A0(ta+2)
        ldB(0, 1);
        stA0(0, ta + 2);
        bar();
        mmaq(0, 1);
        bar();
        // P3: reads A1a (8) | stage B0(ta+2)
        ldA(0, 1);
        stB0(0, ta + 2);
        bar();
        mmaq(1, 0);
        bar();
        // P4: no reads | stage B1(ta+2) | drain depth-6
        stB1(0, ta + 2);
        asm volatile("s_waitcnt vmcnt(6)" ::: "memory");
        bar();
        mmaq(1, 1);
        bar();
        // P5: reads A0b,B0b (12) | stage A1(ta+2)
        ldA(1, 0); ldB(1, 0);
        stA1(0, ta + 2);
        asm volatile("s_waitcnt lgkmcnt(8)" ::: "memory");
        bar();
        mmaq(0, 0);
        bar();
        // P6: reads B1b (4) | stage A0(tb+2)
        ldB(1, 1);
        stA0(1, tb + 2);
        bar();
        mmaq(0, 1);
        bar();
        // P7: reads A1b (8) | stage B0(tb+2)
        ldA(1, 1);
        stB0(1, tb + 2);
        bar();
        mmaq(1, 0);
        bar();
        // P8: no reads | stage B1(tb+2) | drain depth-6
        stB1(1, tb + 2);
        asm volatile("s_waitcnt vmcnt(6)" ::: "memory");
        bar();
        mmaq(1, 1);
        bar();
    }

    // ---- last iteration (j = J-1): only P1's A1(tb) stage; full drain at P4 ----
    {
        const int tb = NT - 1;
        // P1
        ldA(0, 0); ldB(0, 0);
        stA1(1, tb);
        asm volatile("s_waitcnt lgkmcnt(8)" ::: "memory");
        bar();
        mmaq(0, 0);
        bar();
        // P2
        ldB(0, 1);
        bar();
        mmaq(0, 1);
        bar();
        // P3
        ldA(0, 1);
        bar();
        mmaq(1, 0);
        bar();
        // P4: final drain
        asm volatile("s_waitcnt vmcnt(0)" ::: "memory");
        bar();
        mmaq(1, 1);
        bar();
        // P5
        ldA(1, 0); ldB(1, 0);
        bar();
        mmaq(0, 0);
        bar();
        // P6
        ldB(1, 1);
        bar();
        mmaq(0, 1);
        bar();
        // P7
        ldA(1, 1);
        bar();
        mmaq(1, 0);
        bar();
        // P8
        mmaq(1, 1);
    }

    // ---- epilogue: C layout col = lane&15, row = (lane>>4)*4 + reg ----
    const long crow0 = m0 + wm + ((lane >> 4) << 2);
    const int ccol0 = n0 + wn + (lane & 15);
#pragma unroll
    for (int fi = 0; fi < 8; fi++) {
#pragma unroll
        for (int r = 0; r < 4; r++) {
            const size_t rowoff = (size_t)(crow0 + fi * 16 + r) * N;
#pragma unroll
            for (int fj = 0; fj < 4; fj++) {
                float v = acc[fi][fj][r];
                if (ACT) v = fmaxf(v, 0.f) + __logf(1.f + __expf(-fabsf(v)));
                if (OUTF32) Cf[rowoff + ccol0 + fj * 16] = v;
                else        Ch[rowoff + ccol0 + fj * 16] = f2h(v);
            }
        }
    }
}

// ---------------- launch ----------------
extern "C" void kernel_launch(void* const* d_in, const int* in_sizes, int n_in,
                              void* d_out, int out_size, void* d_ws, size_t ws_size,
                              hipStream_t stream) {
    const float* x  = (const float*)d_in[0];
    const float* v1 = (const float*)d_in[1];
    const float* g1 = (const float*)d_in[2];
    const float* v2 = (const float*)d_in[3];
    const float* g2 = (const float*)d_in[4];
    const float* v3 = (const float*)d_in[5];
    const float* g3 = (const float*)d_in[6];
    const float* v4 = (const float*)d_in[7];
    const float* g4 = (const float*)d_in[8];
    const float* v5 = (const float*)d_in[9];
    const float* g5 = (const float*)d_in[10];
    float* out = (float*)d_out;

    const int M = 65536;
    char* ws = (char*)d_ws;
    u16* bufA = (u16*)(ws);                          // 128 MB
    u16* bufB = (u16*)(ws + 0x8000000ULL);           // 128 MB
    u16* w1T  = (u16*)(ws + 0x10000000ULL);
    u16* w2T  = w1T + 1024 * 512;
    u16* w3T  = w2T + 1024 * 1024;
    u16* w4T  = w3T + 1024 * 1024;
    u16* w5T  = w4T + 1024 * 1024;
    float* part = (float*)(ws + 0x10800000ULL);      // 5 x 8 x 1024 f32

    cvt_x_kernel<<<(M * 512) / (256 * 8), 256, 0, stream>>>((const float4*)x, bufB);

    WnPack pk;
    int cum = 0;
    auto mk = [&](int i, const float* v, const float* g, u16* wT, int K, int N) {
        pk.d[i] = WnDesc{v, g, wT, part + i * 8 * 1024, K, N, cum};
        cum += (N / 64) * 8;
    };
    mk(0, v1, g1, w1T, 512, 1024);
    mk(1, v2, g2, w2T, 1024, 1024);
    mk(2, v3, g3, w3T, 1024, 1024);
    mk(3, v4, g4, w4T, 1024, 1024);
    mk(4, v5, g5, w5T, 1024, 512);
    pk.nlayer = 5;

    wn_partial_all<<<cum, 256, 0, stream>>>(pk);
    wn_write_all<<<cum, 256, 0, stream>>>(pk);

    gemm_mlp<1024, 512,  true,  false><<<1024, 512, 0, stream>>>(bufB, w1T, bufA, nullptr);
    gemm_mlp<1024, 1024, true,  false><<<1024, 512, 0, stream>>>(bufA, w2T, bufB, nullptr);
    gemm_mlp<1024, 1024, true,  false><<<1024, 512, 0, stream>>>(bufB, w3T, bufA, nullptr);
    gemm_mlp<1024, 1024, true,  false><<<1024, 512, 0, stream>>>(bufA, w4T, bufB, nullptr);
    gemm_mlp<512,  1024, false, true ><<<512,  512, 0, stream>>>(bufB, w5T, nullptr, out);

    (void)in_sizes; (void)n_in; (void)out_size; (void)ws_size;
}

// Round 7
// 717.519 us; speedup vs baseline: 1.0053x; 1.0053x over previous
//
#include <hip/hip_runtime.h>
#include <hip/hip_bf16.h>
#include <cstdint>

typedef unsigned short u16;
typedef __attribute__((ext_vector_type(8))) _Float16 f16x8;
typedef __attribute__((ext_vector_type(4))) float f32x4;
typedef __attribute__((ext_vector_type(8))) unsigned short u16x8;

typedef const __attribute__((address_space(1))) void* gas1p;
typedef __attribute__((address_space(3))) void* las3p;
typedef const __attribute__((address_space(3))) u16* lc16p;

__device__ __forceinline__ void gld_lds16(const void* g, void* l) {
    __builtin_amdgcn_global_load_lds((gas1p)g, (las3p)l, 16, 0, 0);
}

// inline-asm ds_read_b128: invisible to the waitcnt legalizer, so no
// compiler-inserted vmcnt(0) drains against outstanding global_load_lds.
// RAW vs staging is guaranteed ONLY by our explicit vmcnt waits (ledger below).
__device__ __forceinline__ f16x8 dsr128(const u16* p) {
    f16x8 r;
    asm volatile("ds_read_b128 %0, %1" : "=&v"(r) : "v"((lc16p)p));
    return r;
}

__device__ __forceinline__ u16 f2h(float f) {
    _Float16 h = (_Float16)f;
    return __builtin_bit_cast(u16, h);
}

// ---------------- prep: x fp32 -> fp16 ----------------
__global__ void cvt_x_kernel(const float4* __restrict__ x, u16* __restrict__ xb) {
    size_t i = (size_t)blockIdx.x * blockDim.x + threadIdx.x;
    float4 a = x[2 * i];
    float4 b = x[2 * i + 1];
    u16x8 o;
    o[0] = f2h(a.x); o[1] = f2h(a.y); o[2] = f2h(a.z); o[3] = f2h(a.w);
    o[4] = f2h(b.x); o[5] = f2h(b.y); o[6] = f2h(b.z); o[7] = f2h(b.w);
    *(u16x8*)&xb[i * 8] = o;
}

// ---------------- prep: weight norm, all 5 layers in 2 launches ----------------
struct WnDesc {
    const float* v; const float* g; u16* wT; float* partial;
    int K; int N; int blk0;
};
struct WnPack { WnDesc d[5]; int nlayer; };

__global__ void wn_partial_all(WnPack p) {
    int b = blockIdx.x;
    int l = 0;
    while (l + 1 < p.nlayer && b >= p.d[l + 1].blk0) l++;
    const WnDesc& d = p.d[l];
    int lb = b - d.blk0;
    int nbx = d.N >> 6;
    int bx = lb % nbx, seg = lb / nbx;

    int lane = threadIdx.x & 63;
    int tr = threadIdx.x >> 6;
    int n = bx * 64 + lane;
    int kseg = d.K >> 3;
    int kbeg = seg * kseg;
    float s = 0.f;
    for (int k = kbeg + tr; k < kbeg + kseg; k += 4) {
        float x = d.v[(size_t)k * d.N + n];
        s += x * x;
    }
    __shared__ float red[4][64];
    red[tr][lane] = s;
    __syncthreads();
    if (tr == 0)
        d.partial[seg * d.N + n] = red[0][lane] + red[1][lane] + red[2][lane] + red[3][lane];
}

__global__ void wn_write_all(WnPack p) {
    int b = blockIdx.x;
    int l = 0;
    while (l + 1 < p.nlayer && b >= p.d[l + 1].blk0) l++;
    const WnDesc& d = p.d[l];
    int lb = b - d.blk0;
    int nbx = d.N >> 6;
    int bx = lb % nbx, seg = lb / nbx;

    int lane = threadIdx.x & 63;
    int tr = threadIdx.x >> 6;
    int n = bx * 64 + lane;
    float s = 0.f;
#pragma unroll
    for (int i = 0; i < 8; i++) s += d.partial[i * d.N + n];
    float sc = d.g[n] / sqrtf(s);

    int kseg = d.K >> 3;
    int kbeg = seg * kseg;
    for (int k = kbeg + tr; k < kbeg + kseg; k += 4)
        d.wT[(size_t)n * d.K + k] = f2h(d.v[(size_t)k * d.N + n] * sc);
}

// ---------------- main GEMM: 256x256, BK=64, 8 waves, 8-phase, asm ds_read ----
// Phase = { asm ds_reads ; stage(2 gld_lds) ; BAR ; lgkmcnt(0)+sched_barrier ;
//           16 MFMA (setprio) ; BAR }.
// Stage ring, depth-6 counted drains at P4/P8 (the ONLY RAW guarantee now):
//   P1:A1(tb)  P2:A0(ta+2)  P3:B0(ta+2)  P4:B1(ta+2)+vmcnt(6)
//   P5:A1(ta+2) P6:A0(tb+2) P7:B0(tb+2)  P8:B1(tb+2)+vmcnt(6)
// RAW: P8(j-1) vmcnt(6) forces tile-ta's 4 halves (read P1-P3);
//      P4(j)  vmcnt(6) forces tile-tb's 4 halves (read P5-P7).
// WAR: every stage targets a region whose last reader ran >=1 full
//      double-barriered phase earlier (all lgkm(0)s retired before bar2).
template<int N, int K, bool ACT, bool OUTF32>
__global__ __launch_bounds__(512, 2) void gemm_mlp(
    const u16* __restrict__ A, const u16* __restrict__ Bt,
    u16* __restrict__ Ch, float* __restrict__ Cf)
{
    constexpr int M = 65536;
    constexpr int NT = K / 64;      // K-tiles (even, >=4)
    constexpr int J = NT / 2;       // iterations
    constexpr int NTN = N / 256;
    constexpr int NWG = (M / 256) * NTN;

    __shared__ u16 sA[2][256 * 64];
    __shared__ u16 sB[2][2 * 128 * 64];

    const int bid = blockIdx.x;
    const int wk = (bid & 7) * (NWG >> 3) + (bid >> 3);   // bijective: NWG%8==0
    const int tm = wk / NTN, tn = wk % NTN;
    const long m0 = (long)tm * 256;
    const int n0 = tn * 256;

    const int tid = threadIdx.x;
    const int lane = tid & 63;
    const int wid = tid >> 6;
    const int wm = (wid >> 2) * 128;
    const int wn = (wid & 3) * 64;

    const int r8 = tid >> 3;
    const int gcol = ((tid & 7) ^ (r8 & 7)) * 8;
    const u16* Abase = A + (m0 + r8) * (size_t)K + gcol;
    const u16* Bbase = Bt + (size_t)(n0 + ((r8 >> 5) * 64 + (r8 & 31))) * K + gcol;
    const int dst8 = tid * 8;

    const u16* Aq0 = Abase;
    const u16* Aq1 = Abase + (size_t)64 * K;
    const u16* Aq2 = Abase + (size_t)128 * K;
    const u16* Aq3 = Abase + (size_t)192 * K;
    const u16* B00 = Bbase;
    const u16* B01 = Bbase + (size_t)128 * K;
    const u16* B10 = Bbase + (size_t)32 * K;
    const u16* B11 = Bbase + (size_t)160 * K;

    auto stA = [&](int buf, const u16* base, int t, int q) {
        gld_lds16(base + (size_t)t * 64, &sA[buf][q * 4096 + dst8]);
    };
    auto stB = [&](int buf, const u16* base, int t, int s, int c) {
        gld_lds16(base + (size_t)t * 64, &sB[buf][s * 8192 + c * 4096 + dst8]);
    };
    auto stA0 = [&](int buf, int t) { stA(buf, Aq0, t, 0); stA(buf, Aq2, t, 2); };
    auto stA1 = [&](int buf, int t) { stA(buf, Aq1, t, 1); stA(buf, Aq3, t, 3); };
    auto stB0 = [&](int buf, int t) { stB(buf, B00, t, 0, 0); stB(buf, B01, t, 0, 1); };
    auto stB1 = [&](int buf, int t) { stB(buf, B10, t, 1, 0); stB(buf, B11, t, 1, 1); };

    const int rbase = lane & 15;
    const int co0 = ((lane >> 4) ^ (lane & 7)) * 8;
    const int arow0 = (wm + rbase) * 64 + co0;
    const int brow0 = ((wn >> 6) * 32 + rbase) * 64 + co0;

    f32x4 acc[8][4] = {};
    f16x8 a[4][2], bq[2][2][2];

    auto ldA = [&](int buf, int qm) {
#pragma unroll
        for (int i = 0; i < 4; i++) {
            int base = arow0 + (qm * 64 + i * 16) * 64;
            a[i][0] = dsr128(&sA[buf][base]);
            a[i][1] = dsr128(&sA[buf][base ^ 32]);
        }
    };
    auto ldB = [&](int buf, int qn) {
#pragma unroll
        for (int j2 = 0; j2 < 2; j2++) {
            int base = brow0 + qn * 8192 + j2 * 1024;
            bq[qn][j2][0] = dsr128(&sB[buf][base]);
            bq[qn][j2][1] = dsr128(&sB[buf][base ^ 32]);
        }
    };
    auto mmaq = [&](int qm, int qn) {
        __builtin_amdgcn_s_setprio(1);
#pragma unroll
        for (int kk = 0; kk < 2; kk++)
#pragma unroll
            for (int i = 0; i < 4; i++)
#pragma unroll
                for (int j2 = 0; j2 < 2; j2++)
                    acc[qm * 4 + i][qn * 2 + j2] = __builtin_amdgcn_mfma_f32_16x16x32_f16(
                        a[i][kk], bq[qn][j2][kk], acc[qm * 4 + i][qn * 2 + j2], 0, 0, 0);
        __builtin_amdgcn_s_setprio(0);
    };
    auto bar = [&]() {
        asm volatile("" ::: "memory");
        __builtin_amdgcn_s_barrier();
        asm volatile("" ::: "memory");
    };
    // rule #18 fence: wait our asm ds_reads, then pin MFMAs below the wait
    auto lgkm0sb = [&]() {
        asm volatile("s_waitcnt lgkmcnt(0)");
        __builtin_amdgcn_sched_barrier(0);
    };

    // ---- prologue: 7 half-tile stages; vmcnt(6) forces tile0's 4 halves ----
    stA0(0, 0); stB0(0, 0); stB1(0, 0); stA1(0, 0);
    stA0(1, 1); stB0(1, 1); stB1(1, 1);
    asm volatile("s_waitcnt vmcnt(6)" ::: "memory");
    bar();

    // ---- main loop (uniform for j in [0, J-1)) ----
    for (int j = 0; j < J - 1; j++) {
        const int ta = 2 * j, tb = ta + 1;
        // P1: reads A0a,B0a | stage A1(tb)
        ldA(0, 0); ldB(0, 0);
        stA1(1, tb);
        bar(); lgkm0sb();
        mmaq(0, 0);
        bar();
        // P2: reads B1a | stage A0(ta+2)
        ldB(0, 1);
        stA0(0, ta + 2);
        bar(); lgkm0sb();
        mmaq(0, 1);
        bar();
        // P3: reads A1a | stage B0(ta+2)
        ldA(0, 1);
        stB0(0, ta + 2);
        bar(); lgkm0sb();
        mmaq(1, 0);
        bar();
        // P4: stage B1(ta+2) | counted drain depth-6 (forces tb's halves)
        stB1(0, ta + 2);
        asm volatile("s_waitcnt vmcnt(6)" ::: "memory");
        bar();
        mmaq(1, 1);
        bar();
        // P5: reads A0b,B0b | stage A1(ta+2)
        ldA(1, 0); ldB(1, 0);
        stA1(0, ta + 2);
        bar(); lgkm0sb();
        mmaq(0, 0);
        bar();
        // P6: reads B1b | stage A0(tb+2)
        ldB(1, 1);
        stA0(1, tb + 2);
        bar(); lgkm0sb();
        mmaq(0, 1);
        bar();
        // P7: reads A1b | stage B0(tb+2)
        ldA(1, 1);
        stB0(1, tb + 2);
        bar(); lgkm0sb();
        mmaq(1, 0);
        bar();
        // P8: stage B1(tb+2) | counted drain depth-6 (forces (ta+2)'s halves)
        stB1(1, tb + 2);
        asm volatile("s_waitcnt vmcnt(6)" ::: "memory");
        bar();
        mmaq(1, 1);
        bar();
    }

    // ---- last iteration (j = J-1): only P1's A1 stage; full drain at P4 ----
    {
        const int tb = NT - 1;
        ldA(0, 0); ldB(0, 0);
        stA1(1, tb);
        bar(); lgkm0sb();
        mmaq(0, 0);
        bar();
        ldB(0, 1);
        bar(); lgkm0sb();
        mmaq(0, 1);
        bar();
        ldA(0, 1);
        bar(); lgkm0sb();
        mmaq(1, 0);
        bar();
        asm volatile("s_waitcnt vmcnt(0)" ::: "memory");
        bar();
        mmaq(1, 1);
        bar();
        ldA(1, 0); ldB(1, 0);
        bar(); lgkm0sb();
        mmaq(0, 0);
        bar();
        ldB(1, 1);
        bar(); lgkm0sb();
        mmaq(0, 1);
        bar();
        ldA(1, 1);
        bar(); lgkm0sb();
        mmaq(1, 0);
        bar();
        mmaq(1, 1);
    }

    // ---- epilogue: C layout col = lane&15, row = (lane>>4)*4 + reg ----
    const long crow0 = m0 + wm + ((lane >> 4) << 2);
    const int ccol0 = n0 + wn + (lane & 15);
#pragma unroll
    for (int fi = 0; fi < 8; fi++) {
#pragma unroll
        for (int r = 0; r < 4; r++) {
            const size_t rowoff = (size_t)(crow0 + fi * 16 + r) * N;
#pragma unroll
            for (int fj = 0; fj < 4; fj++) {
                float v = acc[fi][fj][r];
                if (ACT) v = fmaxf(v, 0.f) + __logf(1.f + __expf(-fabsf(v)));
                if (OUTF32) Cf[rowoff + ccol0 + fj * 16] = v;
                else        Ch[rowoff + ccol0 + fj * 16] = f2h(v);
            }
        }
    }
}

// ---------------- launch ----------------
extern "C" void kernel_launch(void* const* d_in, const int* in_sizes, int n_in,
                              void* d_out, int out_size, void* d_ws, size_t ws_size,
                              hipStream_t stream) {
    const float* x  = (const float*)d_in[0];
    const float* v1 = (const float*)d_in[1];
    const float* g1 = (const float*)d_in[2];
    const float* v2 = (const float*)d_in[3];
    const float* g2 = (const float*)d_in[4];
    const float* v3 = (const float*)d_in[5];
    const float* g3 = (const float*)d_in[6];
    const float* v4 = (const float*)d_in[7];
    const float* g4 = (const float*)d_in[8];
    const float* v5 = (const float*)d_in[9];
    const float* g5 = (const float*)d_in[10];
    float* out = (float*)d_out;

    const int M = 65536;
    char* ws = (char*)d_ws;
    u16* bufA = (u16*)(ws);                          // 128 MB
    u16* bufB = (u16*)(ws + 0x8000000ULL);           // 128 MB
    u16* w1T  = (u16*)(ws + 0x10000000ULL);
    u16* w2T  = w1T + 1024 * 512;
    u16* w3T  = w2T + 1024 * 1024;
    u16* w4T  = w3T + 1024 * 1024;
    u16* w5T  = w4T + 1024 * 1024;
    float* part = (float*)(ws + 0x10800000ULL);      // 5 x 8 x 1024 f32

    cvt_x_kernel<<<(M * 512) / (256 * 8), 256, 0, stream>>>((const float4*)x, bufB);

    WnPack pk;
    int cum = 0;
    auto mk = [&](int i, const float* v, const float* g, u16* wT, int K, int N) {
        pk.d[i] = WnDesc{v, g, wT, part + i * 8 * 1024, K, N, cum};
        cum += (N / 64) * 8;
    };
    mk(0, v1, g1, w1T, 512, 1024);
    mk(1, v2, g2, w2T, 1024, 1024);
    mk(2, v3, g3, w3T, 1024, 1024);
    mk(3, v4, g4, w4T, 1024, 1024);
    mk(4, v5, g5, w5T, 1024, 512);
    pk.nlayer = 5;

    wn_partial_all<<<cum, 256, 0, stream>>>(pk);
    wn_write_all<<<cum, 256, 0, stream>>>(pk);

    gemm_mlp<1024, 512,  true,  false><<<1024, 512, 0, stream>>>(bufB, w1T, bufA, nullptr);
    gemm_mlp<1024, 1024, true,  false><<<1024, 512, 0, stream>>>(bufA, w2T, bufB, nullptr);
    gemm_mlp<1024, 1024, true,  false><<<1024, 512, 0, stream>>>(bufB, w3T, bufA, nullptr);
    gemm_mlp<1024, 1024, true,  false><<<1024, 512, 0, stream>>>(bufA, w4T, bufB, nullptr);
    gemm_mlp<512,  1024, false, true ><<<512,  512, 0, stream>>>(bufB, w5T, nullptr, out);

    (void)in_sizes; (void)n_in; (void)out_size; (void)ws_size;
}

// Round 8
// 704.926 us; speedup vs baseline: 1.0232x; 1.0179x over previous
//
#include <hip/hip_runtime.h>
#include <hip/hip_bf16.h>
#include <cstdint>

typedef unsigned short u16;
typedef __attribute__((ext_vector_type(8))) _Float16 f16x8;
typedef __attribute__((ext_vector_type(4))) float f32x4;
typedef __attribute__((ext_vector_type(8))) unsigned short u16x8;

typedef const __attribute__((address_space(1))) void* gas1p;
typedef __attribute__((address_space(3))) void* las3p;
typedef const __attribute__((address_space(3))) u16* lc16p;

__device__ __forceinline__ void gld_lds16(const void* g, void* l) {
    __builtin_amdgcn_global_load_lds((gas1p)g, (las3p)l, 16, 0, 0);
}

// asm ds_read_b128: invisible to the waitcnt legalizer (no auto vmcnt(0) drains);
// RAW is enforced ONLY by our explicit counted lgkmcnt/vmcnt waits (ledger below).
__device__ __forceinline__ f16x8 dsr128(const u16* p) {
    f16x8 r;
    asm volatile("ds_read_b128 %0, %1" : "=v"(r) : "v"((lc16p)p));
    return r;
}

__device__ __forceinline__ u16 f2h(float f) {
    _Float16 h = (_Float16)f;
    return __builtin_bit_cast(u16, h);
}

// ---------------- prep: x fp32 -> fp16 ----------------
__global__ void cvt_x_kernel(const float4* __restrict__ x, u16* __restrict__ xb) {
    size_t i = (size_t)blockIdx.x * blockDim.x + threadIdx.x;
    float4 a = x[2 * i];
    float4 b = x[2 * i + 1];
    u16x8 o;
    o[0] = f2h(a.x); o[1] = f2h(a.y); o[2] = f2h(a.z); o[3] = f2h(a.w);
    o[4] = f2h(b.x); o[5] = f2h(b.y); o[6] = f2h(b.z); o[7] = f2h(b.w);
    *(u16x8*)&xb[i * 8] = o;
}

// ---------------- prep: weight norm, all 5 layers in 2 launches ----------------
struct WnDesc {
    const float* v; const float* g; u16* wT; float* partial;
    int K; int N; int blk0;
};
struct WnPack { WnDesc d[5]; int nlayer; };

__global__ void wn_partial_all(WnPack p) {
    int b = blockIdx.x;
    int l = 0;
    while (l + 1 < p.nlayer && b >= p.d[l + 1].blk0) l++;
    const WnDesc& d = p.d[l];
    int lb = b - d.blk0;
    int nbx = d.N >> 6;
    int bx = lb % nbx, seg = lb / nbx;

    int lane = threadIdx.x & 63;
    int tr = threadIdx.x >> 6;
    int n = bx * 64 + lane;
    int kseg = d.K >> 3;
    int kbeg = seg * kseg;
    float s = 0.f;
    for (int k = kbeg + tr; k < kbeg + kseg; k += 4) {
        float x = d.v[(size_t)k * d.N + n];
        s += x * x;
    }
    __shared__ float red[4][64];
    red[tr][lane] = s;
    __syncthreads();
    if (tr == 0)
        d.partial[seg * d.N + n] = red[0][lane] + red[1][lane] + red[2][lane] + red[3][lane];
}

__global__ void wn_write_all(WnPack p) {
    int b = blockIdx.x;
    int l = 0;
    while (l + 1 < p.nlayer && b >= p.d[l + 1].blk0) l++;
    const WnDesc& d = p.d[l];
    int lb = b - d.blk0;
    int nbx = d.N >> 6;
    int bx = lb % nbx, seg = lb / nbx;

    int lane = threadIdx.x & 63;
    int tr = threadIdx.x >> 6;
    int n = bx * 64 + lane;
    float s = 0.f;
#pragma unroll
    for (int i = 0; i < 8; i++) s += d.partial[i * d.N + n];
    float sc = d.g[n] / sqrtf(s);

    int kseg = d.K >> 3;
    int kbeg = seg * kseg;
    for (int k = kbeg + tr; k < kbeg + kseg; k += 4)
        d.wT[(size_t)n * d.K + k] = f2h(d.v[(size_t)k * d.N + n] * sc);
}

// ---------------- main GEMM: 256x256, BK=64, 8 waves, read-lookahead 4-phase ---
// Quadrant order per tile t: (00),(01),(10),(11). Counted-lgkm pipeline:
//   P1: dsr b1[4];  stage A0(t+2); BAR; lgkm(4)  [forces a0,b0] ; MM00; BAR
//   P2: dsr a1[8];  stage B0(t+2); BAR; lgkm(8)  [forces b1]    ; MM01; BAR
//   P3: vmcnt(4) [forces tile t+1's 4 halves]; dsr a0'(t+1)[8];
//       BAR; lgkm(8) [forces a1]; MM10; BAR
//   P4: dsr b0'(t+1)[4]; stage A1,B1(t+2); BAR; MM11 [a1,b1 already forced];
//       lgkm(4) [forces a0' — WAR for next P1 stage]; BAR
// MFMA always consumes operands loaded ONE phase earlier; the LDS pipe services
// the new reads underneath the MFMA cluster. Stages at P1/P2/P4 only; every
// region's forcing-lgkm precedes a barrier that precedes its re-staging.
template<int N, int K, bool ACT, bool OUTF32>
__global__ __launch_bounds__(512, 2) void gemm_mlp(
    const u16* __restrict__ A, const u16* __restrict__ Bt,
    u16* __restrict__ Ch, float* __restrict__ Cf)
{
    constexpr int M = 65536;
    constexpr int NT = K / 64;      // K-tiles (>=3)
    constexpr int NTN = N / 256;
    constexpr int NWG = (M / 256) * NTN;

    __shared__ u16 sA[2][256 * 64];
    __shared__ u16 sB[2][2 * 128 * 64];

    const int bid = blockIdx.x;
    const int wk = (bid & 7) * (NWG >> 3) + (bid >> 3);   // bijective: NWG%8==0
    const int tm = wk / NTN, tn = wk % NTN;
    const long m0 = (long)tm * 256;
    const int n0 = tn * 256;

    const int tid = threadIdx.x;
    const int lane = tid & 63;
    const int wid = tid >> 6;
    const int wm = (wid >> 2) * 128;
    const int wn = (wid & 3) * 64;

    const int r8 = tid >> 3;
    const int gcol = ((tid & 7) ^ (r8 & 7)) * 8;
    const u16* Abase = A + (m0 + r8) * (size_t)K + gcol;
    const u16* Bbase = Bt + (size_t)(n0 + ((r8 >> 5) * 64 + (r8 & 31))) * K + gcol;
    const int dst8 = tid * 8;

    // stage lambdas (lean addressing: constants fold into the add chain)
    auto stA0 = [&](int buf, int t) {
        gld_lds16(Abase + (size_t)t * 64, &sA[buf][0 * 4096 + dst8]);
        gld_lds16(Abase + (size_t)128 * K + (size_t)t * 64, &sA[buf][2 * 4096 + dst8]);
    };
    auto stA1 = [&](int buf, int t) {
        gld_lds16(Abase + (size_t)64 * K + (size_t)t * 64, &sA[buf][1 * 4096 + dst8]);
        gld_lds16(Abase + (size_t)192 * K + (size_t)t * 64, &sA[buf][3 * 4096 + dst8]);
    };
    auto stB0 = [&](int buf, int t) {
        gld_lds16(Bbase + (size_t)t * 64, &sB[buf][dst8]);
        gld_lds16(Bbase + (size_t)128 * K + (size_t)t * 64, &sB[buf][4096 + dst8]);
    };
    auto stB1 = [&](int buf, int t) {
        gld_lds16(Bbase + (size_t)32 * K + (size_t)t * 64, &sB[buf][8192 + dst8]);
        gld_lds16(Bbase + (size_t)160 * K + (size_t)t * 64, &sB[buf][8192 + 4096 + dst8]);
    };

    const int rbase = lane & 15;
    const int co0 = ((lane >> 4) ^ (lane & 7)) * 8;
    const int arow0 = (wm + rbase) * 64 + co0;
    const int brow0 = ((wn >> 6) * 32 + rbase) * 64 + co0;

    f32x4 acc[8][4] = {};
    f16x8 rA0[4][2], rA1[4][2], rB0[2][2], rB1[2][2];

    auto dsrA = [&](f16x8 (&r)[4][2], int buf, int qm) {
#pragma unroll
        for (int i = 0; i < 4; i++) {
            int base = arow0 + (qm * 64 + i * 16) * 64;
            r[i][0] = dsr128(&sA[buf][base]);
            r[i][1] = dsr128(&sA[buf][base ^ 32]);
        }
    };
    auto dsrB = [&](f16x8 (&r)[2][2], int buf, int qn) {
#pragma unroll
        for (int j2 = 0; j2 < 2; j2++) {
            int base = brow0 + qn * 8192 + j2 * 1024;
            r[j2][0] = dsr128(&sB[buf][base]);
            r[j2][1] = dsr128(&sB[buf][base ^ 32]);
        }
    };
    auto mm = [&](f16x8 (&ra)[4][2], f16x8 (&rb)[2][2], int qm, int qn) {
        __builtin_amdgcn_s_setprio(1);
#pragma unroll
        for (int kk = 0; kk < 2; kk++)
#pragma unroll
            for (int i = 0; i < 4; i++)
#pragma unroll
                for (int j2 = 0; j2 < 2; j2++)
                    acc[qm * 4 + i][qn * 2 + j2] = __builtin_amdgcn_mfma_f32_16x16x32_f16(
                        ra[i][kk], rb[j2][kk], acc[qm * 4 + i][qn * 2 + j2], 0, 0, 0);
        __builtin_amdgcn_s_setprio(0);
    };
    auto BAR = [&]() {
        asm volatile("" ::: "memory");
        __builtin_amdgcn_s_barrier();
        asm volatile("" ::: "memory");
    };
#define LGKM(n) { asm volatile("s_waitcnt lgkmcnt(" #n ")"); __builtin_amdgcn_sched_barrier(0); }

    // ---- prologue: stage tiles 0,1; force t0; pre-read a0,b0 of t0 ----
    stA0(0, 0); stB0(0, 0); stA1(0, 0); stB1(0, 0);
    stA0(1, 1); stB0(1, 1); stA1(1, 1); stB1(1, 1);
    asm volatile("s_waitcnt vmcnt(8)" ::: "memory");
    BAR();
    dsrA(rA0, 0, 0); dsrB(rB0, 0, 0);
    LGKM(0);
    BAR();

    // ---- main loop: tiles 0 .. NT-3 (uniform body) ----
    for (int t = 0; t < NT - 2; t++) {
        const int cur = t & 1, nxt = cur ^ 1;
        // P1
        dsrB(rB1, cur, 1);
        stA0(cur, t + 2);
        BAR(); LGKM(4);
        mm(rA0, rB0, 0, 0);
        BAR();
        // P2
        dsrA(rA1, cur, 1);
        stB0(cur, t + 2);
        BAR(); LGKM(8);
        mm(rA0, rB1, 0, 1);
        BAR();
        // P3
        asm volatile("s_waitcnt vmcnt(4)" ::: "memory");
        dsrA(rA0, nxt, 0);
        BAR(); LGKM(8);
        mm(rA1, rB0, 1, 0);
        BAR();
        // P4
        dsrB(rB0, nxt, 0);
        stA1(cur, t + 2); stB1(cur, t + 2);
        BAR();
        mm(rA1, rB1, 1, 1);
        LGKM(4);
        BAR();
    }
    // ---- t = NT-2: no stages; full drain before reading t+1 ----
    {
        const int cur = (NT - 2) & 1, nxt = cur ^ 1;
        dsrB(rB1, cur, 1);
        BAR(); LGKM(4);
        mm(rA0, rB0, 0, 0);
        BAR();
        dsrA(rA1, cur, 1);
        BAR(); LGKM(8);
        mm(rA0, rB1, 0, 1);
        BAR();
        asm volatile("s_waitcnt vmcnt(0)" ::: "memory");
        dsrA(rA0, nxt, 0);
        BAR(); LGKM(8);
        mm(rA1, rB0, 1, 0);
        BAR();
        dsrB(rB0, nxt, 0);
        BAR();
        mm(rA1, rB1, 1, 1);
        LGKM(4);
        BAR();
    }
    // ---- t = NT-1: final tile, no stages/vmcnt ----
    {
        const int cur = (NT - 1) & 1;
        dsrB(rB1, cur, 1);
        BAR(); LGKM(4);
        mm(rA0, rB0, 0, 0);
        BAR();
        dsrA(rA1, cur, 1);
        BAR(); LGKM(8);
        mm(rA0, rB1, 0, 1);
        BAR();
        LGKM(0);
        mm(rA1, rB0, 1, 0);
        mm(rA1, rB1, 1, 1);
    }
#undef LGKM

    // ---- epilogue: C layout col = lane&15, row = (lane>>4)*4 + reg ----
    const long crow0 = m0 + wm + ((lane >> 4) << 2);
    const int ccol0 = n0 + wn + (lane & 15);
#pragma unroll
    for (int fi = 0; fi < 8; fi++) {
#pragma unroll
        for (int r = 0; r < 4; r++) {
            const size_t rowoff = (size_t)(crow0 + fi * 16 + r) * N;
#pragma unroll
            for (int fj = 0; fj < 4; fj++) {
                float v = acc[fi][fj][r];
                if (ACT) v = fmaxf(v, 0.f) + __logf(1.f + __expf(-fabsf(v)));
                if (OUTF32) Cf[rowoff + ccol0 + fj * 16] = v;
                else        Ch[rowoff + ccol0 + fj * 16] = f2h(v);
            }
        }
    }
}

// ---------------- launch ----------------
extern "C" void kernel_launch(void* const* d_in, const int* in_sizes, int n_in,
                              void* d_out, int out_size, void* d_ws, size_t ws_size,
                              hipStream_t stream) {
    const float* x  = (const float*)d_in[0];
    const float* v1 = (const float*)d_in[1];
    const float* g1 = (const float*)d_in[2];
    const float* v2 = (const float*)d_in[3];
    const float* g2 = (const float*)d_in[4];
    const float* v3 = (const float*)d_in[5];
    const float* g3 = (const float*)d_in[6];
    const float* v4 = (const float*)d_in[7];
    const float* g4 = (const float*)d_in[8];
    const float* v5 = (const float*)d_in[9];
    const float* g5 = (const float*)d_in[10];
    float* out = (float*)d_out;

    const int M = 65536;
    char* ws = (char*)d_ws;
    u16* bufA = (u16*)(ws);                          // 128 MB
    u16* bufB = (u16*)(ws + 0x8000000ULL);           // 128 MB
    u16* w1T  = (u16*)(ws + 0x10000000ULL);
    u16* w2T  = w1T + 1024 * 512;
    u16* w3T  = w2T + 1024 * 1024;
    u16* w4T  = w3T + 1024 * 1024;
    u16* w5T  = w4T + 1024 * 1024;
    float* part = (float*)(ws + 0x10800000ULL);      // 5 x 8 x 1024 f32

    cvt_x_kernel<<<(M * 512) / (256 * 8), 256, 0, stream>>>((const float4*)x, bufB);

    WnPack pk;
    int cum = 0;
    auto mk = [&](int i, const float* v, const float* g, u16* wT, int K, int N) {
        pk.d[i] = WnDesc{v, g, wT, part + i * 8 * 1024, K, N, cum};
        cum += (N / 64) * 8;
    };
    mk(0, v1, g1, w1T, 512, 1024);
    mk(1, v2, g2, w2T, 1024, 1024);
    mk(2, v3, g3, w3T, 1024, 1024);
    mk(3, v4, g4, w4T, 1024, 1024);
    mk(4, v5, g5, w5T, 1024, 512);
    pk.nlayer = 5;

    wn_partial_all<<<cum, 256, 0, stream>>>(pk);
    wn_write_all<<<cum, 256, 0, stream>>>(pk);

    gemm_mlp<1024, 512,  true,  false><<<1024, 512, 0, stream>>>(bufB, w1T, bufA, nullptr);
    gemm_mlp<1024, 1024, true,  false><<<1024, 512, 0, stream>>>(bufA, w2T, bufB, nullptr);
    gemm_mlp<1024, 1024, true,  false><<<1024, 512, 0, stream>>>(bufB, w3T, bufA, nullptr);
    gemm_mlp<1024, 1024, true,  false><<<1024, 512, 0, stream>>>(bufA, w4T, bufB, nullptr);
    gemm_mlp<512,  1024, false, true ><<<512,  512, 0, stream>>>(bufB, w5T, nullptr, out);

    (void)in_sizes; (void)n_in; (void)out_size; (void)ws_size;
}

// Round 9
// 704.189 us; speedup vs baseline: 1.0243x; 1.0010x over previous
//
#include <hip/hip_runtime.h>
#include <hip/hip_bf16.h>
#include <cstdint>

typedef unsigned short u16;
typedef __attribute__((ext_vector_type(8))) _Float16 f16x8;
typedef __attribute__((ext_vector_type(4))) float f32x4;
typedef __attribute__((ext_vector_type(8))) unsigned short u16x8;

typedef const __attribute__((address_space(1))) void* gas1p;
typedef __attribute__((address_space(3))) void* las3p;
typedef const __attribute__((address_space(3))) u16* lc16p;

__device__ __forceinline__ void gld_lds16(const void* g, void* l) {
    __builtin_amdgcn_global_load_lds((gas1p)g, (las3p)l, 16, 0, 0);
}

// asm ds_read_b128 / s_waitcnt WITHOUT memory clobbers: a "memory" clobber makes
// the asm mayLoad/mayStore ALL memory (incl. LDS), forcing the waitcnt legalizer
// to insert protective s_waitcnt vmcnt(0) against outstanding global_load_lds
// before every barrier -- silently reducing every counted-vmcnt schedule to
// drain-everything (the R2..R8 36% plateau). Clobber-free volatile asm keeps
// program order vs other side-effecting ops; RAW/WAR is OUR ledger's job.
__device__ __forceinline__ f16x8 dsr128(const u16* p) {
    f16x8 r;
    asm volatile("ds_read_b128 %0, %1" : "=v"(r) : "v"((lc16p)p));
    return r;
}

__device__ __forceinline__ u16 f2h(float f) {
    _Float16 h = (_Float16)f;
    return __builtin_bit_cast(u16, h);
}

// ---------------- prep: x fp32 -> fp16 ----------------
__global__ void cvt_x_kernel(const float4* __restrict__ x, u16* __restrict__ xb) {
    size_t i = (size_t)blockIdx.x * blockDim.x + threadIdx.x;
    float4 a = x[2 * i];
    float4 b = x[2 * i + 1];
    u16x8 o;
    o[0] = f2h(a.x); o[1] = f2h(a.y); o[2] = f2h(a.z); o[3] = f2h(a.w);
    o[4] = f2h(b.x); o[5] = f2h(b.y); o[6] = f2h(b.z); o[7] = f2h(b.w);
    *(u16x8*)&xb[i * 8] = o;
}

// ---------------- prep: weight norm, all 5 layers in 2 launches ----------------
struct WnDesc {
    const float* v; const float* g; u16* wT; float* partial;
    int K; int N; int blk0;
};
struct WnPack { WnDesc d[5]; int nlayer; };

__global__ void wn_partial_all(WnPack p) {
    int b = blockIdx.x;
    int l = 0;
    while (l + 1 < p.nlayer && b >= p.d[l + 1].blk0) l++;
    const WnDesc& d = p.d[l];
    int lb = b - d.blk0;
    int nbx = d.N >> 6;
    int bx = lb % nbx, seg = lb / nbx;

    int lane = threadIdx.x & 63;
    int tr = threadIdx.x >> 6;
    int n = bx * 64 + lane;
    int kseg = d.K >> 3;
    int kbeg = seg * kseg;
    float s = 0.f;
    for (int k = kbeg + tr; k < kbeg + kseg; k += 4) {
        float x = d.v[(size_t)k * d.N + n];
        s += x * x;
    }
    __shared__ float red[4][64];
    red[tr][lane] = s;
    __syncthreads();
    if (tr == 0)
        d.partial[seg * d.N + n] = red[0][lane] + red[1][lane] + red[2][lane] + red[3][lane];
}

__global__ void wn_write_all(WnPack p) {
    int b = blockIdx.x;
    int l = 0;
    while (l + 1 < p.nlayer && b >= p.d[l + 1].blk0) l++;
    const WnDesc& d = p.d[l];
    int lb = b - d.blk0;
    int nbx = d.N >> 6;
    int bx = lb % nbx, seg = lb / nbx;

    int lane = threadIdx.x & 63;
    int tr = threadIdx.x >> 6;
    int n = bx * 64 + lane;
    float s = 0.f;
#pragma unroll
    for (int i = 0; i < 8; i++) s += d.partial[i * d.N + n];
    float sc = d.g[n] / sqrtf(s);

    int kseg = d.K >> 3;
    int kbeg = seg * kseg;
    for (int k = kbeg + tr; k < kbeg + kseg; k += 4)
        d.wT[(size_t)n * d.K + k] = f2h(d.v[(size_t)k * d.N + n] * sc);
}

// ---------------- main GEMM: 256x256, BK=64, 8 waves, read-lookahead 4-phase ---
// Identical structure to R8; ONLY change: all barriers are bare
// __builtin_amdgcn_s_barrier() and all s_waitcnt asm is clobber-free, so the
// counted vmcnt/lgkm waits actually survive into the emitted code.
// Ledger (unchanged, re-verified):
//   P1: dsr b1[4];  stage A0(t+2); BAR; lgkm(4)  -> forces a0,b0 ; MM00; BAR
//   P2: dsr a1[8];  stage B0(t+2); BAR; lgkm(8)  -> forces b1    ; MM01; BAR
//   P3: vmcnt(4) -> forces tile t+1's 4 halves;  dsr a0'(t+1)[8];
//       BAR; lgkm(8) -> forces a1; MM10; BAR
//   P4: dsr b0'(t+1)[4]; stage A1,B1(t+2); BAR; MM11; lgkm(4) -> forces a0'; BAR
template<int N, int K, bool ACT, bool OUTF32>
__global__ __launch_bounds__(512, 2) void gemm_mlp(
    const u16* __restrict__ A, const u16* __restrict__ Bt,
    u16* __restrict__ Ch, float* __restrict__ Cf)
{
    constexpr int M = 65536;
    constexpr int NT = K / 64;      // K-tiles (>=3)
    constexpr int NTN = N / 256;
    constexpr int NWG = (M / 256) * NTN;

    __shared__ u16 sA[2][256 * 64];
    __shared__ u16 sB[2][2 * 128 * 64];

    const int bid = blockIdx.x;
    const int wk = (bid & 7) * (NWG >> 3) + (bid >> 3);   // bijective: NWG%8==0
    const int tm = wk / NTN, tn = wk % NTN;
    const long m0 = (long)tm * 256;
    const int n0 = tn * 256;

    const int tid = threadIdx.x;
    const int lane = tid & 63;
    const int wid = tid >> 6;
    const int wm = (wid >> 2) * 128;
    const int wn = (wid & 3) * 64;

    const int r8 = tid >> 3;
    const int gcol = ((tid & 7) ^ (r8 & 7)) * 8;
    const u16* Abase = A + (m0 + r8) * (size_t)K + gcol;
    const u16* Bbase = Bt + (size_t)(n0 + ((r8 >> 5) * 64 + (r8 & 31))) * K + gcol;
    const int dst8 = tid * 8;

    auto stA0 = [&](int buf, int t) {
        gld_lds16(Abase + (size_t)t * 64, &sA[buf][0 * 4096 + dst8]);
        gld_lds16(Abase + (size_t)128 * K + (size_t)t * 64, &sA[buf][2 * 4096 + dst8]);
    };
    auto stA1 = [&](int buf, int t) {
        gld_lds16(Abase + (size_t)64 * K + (size_t)t * 64, &sA[buf][1 * 4096 + dst8]);
        gld_lds16(Abase + (size_t)192 * K + (size_t)t * 64, &sA[buf][3 * 4096 + dst8]);
    };
    auto stB0 = [&](int buf, int t) {
        gld_lds16(Bbase + (size_t)t * 64, &sB[buf][dst8]);
        gld_lds16(Bbase + (size_t)128 * K + (size_t)t * 64, &sB[buf][4096 + dst8]);
    };
    auto stB1 = [&](int buf, int t) {
        gld_lds16(Bbase + (size_t)32 * K + (size_t)t * 64, &sB[buf][8192 + dst8]);
        gld_lds16(Bbase + (size_t)160 * K + (size_t)t * 64, &sB[buf][8192 + 4096 + dst8]);
    };

    const int rbase = lane & 15;
    const int co0 = ((lane >> 4) ^ (lane & 7)) * 8;
    const int arow0 = (wm + rbase) * 64 + co0;
    const int brow0 = ((wn >> 6) * 32 + rbase) * 64 + co0;

    f32x4 acc[8][4] = {};
    f16x8 rA0[4][2], rA1[4][2], rB0[2][2], rB1[2][2];

    auto dsrA = [&](f16x8 (&r)[4][2], int buf, int qm) {
#pragma unroll
        for (int i = 0; i < 4; i++) {
            int base = arow0 + (qm * 64 + i * 16) * 64;
            r[i][0] = dsr128(&sA[buf][base]);
            r[i][1] = dsr128(&sA[buf][base ^ 32]);
        }
    };
    auto dsrB = [&](f16x8 (&r)[2][2], int buf, int qn) {
#pragma unroll
        for (int j2 = 0; j2 < 2; j2++) {
            int base = brow0 + qn * 8192 + j2 * 1024;
            r[j2][0] = dsr128(&sB[buf][base]);
            r[j2][1] = dsr128(&sB[buf][base ^ 32]);
        }
    };
    auto mm = [&](f16x8 (&ra)[4][2], f16x8 (&rb)[2][2], int qm, int qn) {
        __builtin_amdgcn_s_setprio(1);
#pragma unroll
        for (int kk = 0; kk < 2; kk++)
#pragma unroll
            for (int i = 0; i < 4; i++)
#pragma unroll
                for (int j2 = 0; j2 < 2; j2++)
                    acc[qm * 4 + i][qn * 2 + j2] = __builtin_amdgcn_mfma_f32_16x16x32_f16(
                        ra[i][kk], rb[j2][kk], acc[qm * 4 + i][qn * 2 + j2], 0, 0, 0);
        __builtin_amdgcn_s_setprio(0);
    };
    auto BAR = [&]() { __builtin_amdgcn_s_barrier(); };
#define LGKM(n) { asm volatile("s_waitcnt lgkmcnt(" #n ")"); __builtin_amdgcn_sched_barrier(0); }
#define VMCNT(n) { asm volatile("s_waitcnt vmcnt(" #n ")"); __builtin_amdgcn_sched_barrier(0); }

    // ---- prologue: stage tiles 0,1; force t0; pre-read a0,b0 of t0 ----
    stA0(0, 0); stB0(0, 0); stA1(0, 0); stB1(0, 0);
    stA0(1, 1); stB0(1, 1); stA1(1, 1); stB1(1, 1);
    VMCNT(8);
    BAR();
    dsrA(rA0, 0, 0); dsrB(rB0, 0, 0);
    LGKM(0);
    BAR();

    // ---- main loop: tiles 0 .. NT-3 (uniform body) ----
    for (int t = 0; t < NT - 2; t++) {
        const int cur = t & 1, nxt = cur ^ 1;
        // P1
        dsrB(rB1, cur, 1);
        stA0(cur, t + 2);
        BAR(); LGKM(4);
        mm(rA0, rB0, 0, 0);
        BAR();
        // P2
        dsrA(rA1, cur, 1);
        stB0(cur, t + 2);
        BAR(); LGKM(8);
        mm(rA0, rB1, 0, 1);
        BAR();
        // P3
        VMCNT(4);
        dsrA(rA0, nxt, 0);
        BAR(); LGKM(8);
        mm(rA1, rB0, 1, 0);
        BAR();
        // P4
        dsrB(rB0, nxt, 0);
        stA1(cur, t + 2); stB1(cur, t + 2);
        BAR();
        mm(rA1, rB1, 1, 1);
        LGKM(4);
        BAR();
    }
    // ---- t = NT-2: no stages; full drain before reading t+1 ----
    {
        const int cur = (NT - 2) & 1, nxt = cur ^ 1;
        dsrB(rB1, cur, 1);
        BAR(); LGKM(4);
        mm(rA0, rB0, 0, 0);
        BAR();
        dsrA(rA1, cur, 1);
        BAR(); LGKM(8);
        mm(rA0, rB1, 0, 1);
        BAR();
        VMCNT(0);
        dsrA(rA0, nxt, 0);
        BAR(); LGKM(8);
        mm(rA1, rB0, 1, 0);
        BAR();
        dsrB(rB0, nxt, 0);
        BAR();
        mm(rA1, rB1, 1, 1);
        LGKM(4);
        BAR();
    }
    // ---- t = NT-1: final tile, no stages/vmcnt ----
    {
        const int cur = (NT - 1) & 1;
        dsrB(rB1, cur, 1);
        BAR(); LGKM(4);
        mm(rA0, rB0, 0, 0);
        BAR();
        dsrA(rA1, cur, 1);
        BAR(); LGKM(8);
        mm(rA0, rB1, 0, 1);
        BAR();
        LGKM(0);
        mm(rA1, rB0, 1, 0);
        mm(rA1, rB1, 1, 1);
    }
#undef LGKM
#undef VMCNT

    // ---- epilogue: C layout col = lane&15, row = (lane>>4)*4 + reg ----
    const long crow0 = m0 + wm + ((lane >> 4) << 2);
    const int ccol0 = n0 + wn + (lane & 15);
#pragma unroll
    for (int fi = 0; fi < 8; fi++) {
#pragma unroll
        for (int r = 0; r < 4; r++) {
            const size_t rowoff = (size_t)(crow0 + fi * 16 + r) * N;
#pragma unroll
            for (int fj = 0; fj < 4; fj++) {
                float v = acc[fi][fj][r];
                if (ACT) v = fmaxf(v, 0.f) + __logf(1.f + __expf(-fabsf(v)));
                if (OUTF32) Cf[rowoff + ccol0 + fj * 16] = v;
                else        Ch[rowoff + ccol0 + fj * 16] = f2h(v);
            }
        }
    }
}

// ---------------- launch ----------------
extern "C" void kernel_launch(void* const* d_in, const int* in_sizes, int n_in,
                              void* d_out, int out_size, void* d_ws, size_t ws_size,
                              hipStream_t stream) {
    const float* x  = (const float*)d_in[0];
    const float* v1 = (const float*)d_in[1];
    const float* g1 = (const float*)d_in[2];
    const float* v2 = (const float*)d_in[3];
    const float* g2 = (const float*)d_in[4];
    const float* v3 = (const float*)d_in[5];
    const float* g3 = (const float*)d_in[6];
    const float* v4 = (const float*)d_in[7];
    const float* g4 = (const float*)d_in[8];
    const float* v5 = (const float*)d_in[9];
    const float* g5 = (const float*)d_in[10];
    float* out = (float*)d_out;

    const int M = 65536;
    char* ws = (char*)d_ws;
    u16* bufA = (u16*)(ws);                          // 128 MB
    u16* bufB = (u16*)(ws + 0x8000000ULL);           // 128 MB
    u16* w1T  = (u16*)(ws + 0x10000000ULL);
    u16* w2T  = w1T + 1024 * 512;
    u16* w3T  = w2T + 1024 * 1024;
    u16* w4T  = w3T + 1024 * 1024;
    u16* w5T  = w4T + 1024 * 1024;
    float* part = (float*)(ws + 0x10800000ULL);      // 5 x 8 x 1024 f32

    cvt_x_kernel<<<(M * 512) / (256 * 8), 256, 0, stream>>>((const float4*)x, bufB);

    WnPack pk;
    int cum = 0;
    auto mk = [&](int i, const float* v, const float* g, u16* wT, int K, int N) {
        pk.d[i] = WnDesc{v, g, wT, part + i * 8 * 1024, K, N, cum};
        cum += (N / 64) * 8;
    };
    mk(0, v1, g1, w1T, 512, 1024);
    mk(1, v2, g2, w2T, 1024, 1024);
    mk(2, v3, g3, w3T, 1024, 1024);
    mk(3, v4, g4, w4T, 1024, 1024);
    mk(4, v5, g5, w5T, 1024, 512);
    pk.nlayer = 5;

    wn_partial_all<<<cum, 256, 0, stream>>>(pk);
    wn_write_all<<<cum, 256, 0, stream>>>(pk);

    gemm_mlp<1024, 512,  true,  false><<<1024, 512, 0, stream>>>(bufB, w1T, bufA, nullptr);
    gemm_mlp<1024, 1024, true,  false><<<1024, 512, 0, stream>>>(bufA, w2T, bufB, nullptr);
    gemm_mlp<1024, 1024, true,  false><<<1024, 512, 0, stream>>>(bufB, w3T, bufA, nullptr);
    gemm_mlp<1024, 1024, true,  false><<<1024, 512, 0, stream>>>(bufA, w4T, bufB, nullptr);
    gemm_mlp<512,  1024, false, true ><<<512,  512, 0, stream>>>(bufB, w5T, nullptr, out);

    (void)in_sizes; (void)n_in; (void)out_size; (void)ws_size;
}